// Round 1
// baseline (9520.698 us; speedup 1.0000x reference)
//
#include <hip/hip_runtime.h>
#include <math.h>

#define D_  1024
#define T_  1024
#define B_  2
#define H_  16
#define DH_ 64
#define L_  4
#define FF_ 4096
#define V_  32000
#define M_  2048   // B*T tokens

typedef _Float16 f16;
typedef _Float16 f16x8 __attribute__((ext_vector_type(8)));
typedef _Float16 f16x4 __attribute__((ext_vector_type(4)));
typedef float    fx4  __attribute__((ext_vector_type(4)));

// ---------------- fp32 -> fp16 convert (exact-size grid, n % 1024 == 0) ----------------
__global__ __launch_bounds__(256) void f2h_k(const float* __restrict__ in, f16* __restrict__ out) {
    const long i = ((long)blockIdx.x * 256 + threadIdx.x) * 4;
    const float4 v = *(const float4*)(in + i);
    f16x4 o = { (f16)v.x, (f16)v.y, (f16)v.z, (f16)v.w };
    *(f16x4*)(out + i) = o;
}

// ---------------- embedding + positional ----------------
__global__ __launch_bounds__(256) void embed_k(const int* __restrict__ x, const float* __restrict__ emb,
                                               const float* __restrict__ pos, float* __restrict__ h) {
    const long m = blockIdx.x;            // token row 0..2047
    const int  t = threadIdx.x;           // 256 threads * float4 = 1024 floats
    const long tok = x[m];
    const long pt  = m & (T_ - 1);        // m % T
    const float4 e = ((const float4*)(emb + tok * D_))[t];
    const float4 p = ((const float4*)(pos + pt * D_))[t];
    ((float4*)(h + m * D_))[t] = make_float4(e.x + p.x, e.y + p.y, e.z + p.z, e.w + p.w);
}

// ---------------- LayerNorm over D=1024; optional fp32 + fp16 outputs ----------------
__global__ __launch_bounds__(256) void ln_k(const float* __restrict__ x, const float* __restrict__ g,
                                            const float* __restrict__ b, float* __restrict__ of,
                                            f16* __restrict__ oh) {
    const long m = blockIdx.x;
    const int  t = threadIdx.x;
    const int  wave = t >> 6, lane = t & 63;
    __shared__ float red1[4], red2[4];
    const float4 v = ((const float4*)(x + m * D_))[t];
    float s = v.x + v.y + v.z + v.w;
#pragma unroll
    for (int off = 32; off; off >>= 1) s += __shfl_xor(s, off, 64);
    if (lane == 0) red1[wave] = s;
    __syncthreads();
    const float mean = (red1[0] + red1[1] + red1[2] + red1[3]) * (1.0f / 1024.0f);
    const float d0 = v.x - mean, d1 = v.y - mean, d2 = v.z - mean, d3 = v.w - mean;
    float s2 = d0 * d0 + d1 * d1 + d2 * d2 + d3 * d3;
#pragma unroll
    for (int off = 32; off; off >>= 1) s2 += __shfl_xor(s2, off, 64);
    if (lane == 0) red2[wave] = s2;
    __syncthreads();
    const float var  = (red2[0] + red2[1] + red2[2] + red2[3]) * (1.0f / 1024.0f);
    const float rstd = rsqrtf(var + 1e-5f);
    const float4 gv = ((const float4*)g)[t];
    const float4 bv = ((const float4*)b)[t];
    const float o0 = d0 * rstd * gv.x + bv.x;
    const float o1 = d1 * rstd * gv.y + bv.y;
    const float o2 = d2 * rstd * gv.z + bv.z;
    const float o3 = d3 * rstd * gv.w + bv.w;
    if (of) ((float4*)(of + m * D_))[t] = make_float4(o0, o1, o2, o3);
    if (oh) { f16x4 o = { (f16)o0, (f16)o1, (f16)o2, (f16)o3 }; *(f16x4*)(oh + m * D_ + t * 4) = o; }
}

// ---------------- elementwise helpers ----------------
__global__ __launch_bounds__(256) void sub_k(const float* __restrict__ a, const float* __restrict__ b,
                                             f16* __restrict__ o) {   // o = f16(a - b)
    const long i = ((long)blockIdx.x * 256 + threadIdx.x) * 4;
    const float4 va = *(const float4*)(a + i);
    const float4 vb = *(const float4*)(b + i);
    f16x4 o4 = { (f16)(va.x - vb.x), (f16)(va.y - vb.y), (f16)(va.z - vb.z), (f16)(va.w - vb.w) };
    *(f16x4*)(o + i) = o4;
}

__global__ __launch_bounds__(256) void cat_k(const float* __restrict__ p, const float* __restrict__ c,
                                             f16* __restrict__ o) {   // o[m, 0:1024]=p[m], o[m,1024:2048]=c[m]
    const long i = ((long)blockIdx.x * 256 + threadIdx.x) * 4;        // over 2048*2048
    const long m = i >> 11;
    const int  j = (int)(i & 2047);
    const float* src = (j < 1024) ? (p + m * 1024 + j) : (c + m * 1024 + (j - 1024));
    const float4 v = *(const float4*)src;
    f16x4 o4 = { (f16)v.x, (f16)v.y, (f16)v.z, (f16)v.w };
    *(f16x4*)(o + i) = o4;
}

__global__ __launch_bounds__(256) void gate_k(const float* __restrict__ p, const float* __restrict__ c,
                                              const float* __restrict__ gl, f16* __restrict__ o) {
    // o = f16(pred + sigmoid(glin) * corr)
    const long i = ((long)blockIdx.x * 256 + threadIdx.x) * 4;
    const float4 vp = *(const float4*)(p + i);
    const float4 vc = *(const float4*)(c + i);
    const float4 vg = *(const float4*)(gl + i);
    const float s0 = 1.0f / (1.0f + __expf(-vg.x));
    const float s1 = 1.0f / (1.0f + __expf(-vg.y));
    const float s2 = 1.0f / (1.0f + __expf(-vg.z));
    const float s3 = 1.0f / (1.0f + __expf(-vg.w));
    f16x4 o4 = { (f16)(vp.x + s0 * vc.x), (f16)(vp.y + s1 * vc.y),
                 (f16)(vp.z + s2 * vc.z), (f16)(vp.w + s3 * vc.w) };
    *(f16x4*)(o + i) = o4;
}

// ---------------- GEMM: C(M,N) = A(M,K) @ W(N,K)^T [+bias] [+resid | gelu->f16] ----------------
// m97 structure: 128x128 tile, BK=32, 4 waves 2x2, each wave 4x4 of 16x16x32 MFMA,
// global_load_lds width=16 staging (LDS layout == global lane order, no padding).
__global__ __launch_bounds__(256)
void gemm_bt(const f16* __restrict__ A, const f16* __restrict__ Wt,
             const float* __restrict__ bias, const float* __restrict__ resid,
             float* __restrict__ Cf, f16* __restrict__ Ch,
             int N, int K, int gelu) {
    __shared__ __align__(16) f16 As[128 * 32];
    __shared__ __align__(16) f16 Bs[128 * 32];
    const int tid  = threadIdx.x;
    const int wave = tid >> 6;
    const int lane = tid & 63;
    const long bm = blockIdx.y;
    const long bn = blockIdx.x;
    const int wm = (wave >> 1) * 64;
    const int wn = (wave & 1) * 64;

    fx4 acc[4][4] = {};

    // staging: chunk c = wave*2 + {0,1}; lane covers row c*16 + lane/4, col (lane&3)*8 of the 128x32 tile
    const int c0 = wave * 2;
    const int r0 = c0 * 16 + (lane >> 2);
    const int cc = (lane & 3) * 8;
    const f16* a0 = A  + ((long)bm * 128 + r0) * K + cc;
    const f16* a1 = A  + ((long)bm * 128 + r0 + 16) * K + cc;
    const f16* b0 = Wt + ((long)bn * 128 + r0) * K + cc;
    const f16* b1 = Wt + ((long)bn * 128 + r0 + 16) * K + cc;
    f16* sa0 = &As[c0 * 512];
    f16* sa1 = &As[(c0 + 1) * 512];
    f16* sb0 = &Bs[c0 * 512];
    f16* sb1 = &Bs[(c0 + 1) * 512];

    for (int k0 = 0; k0 < K; k0 += 32) {
        __builtin_amdgcn_global_load_lds((const __attribute__((address_space(1))) void*)(a0 + k0),
                                         (__attribute__((address_space(3))) void*)sa0, 16, 0, 0);
        __builtin_amdgcn_global_load_lds((const __attribute__((address_space(1))) void*)(a1 + k0),
                                         (__attribute__((address_space(3))) void*)sa1, 16, 0, 0);
        __builtin_amdgcn_global_load_lds((const __attribute__((address_space(1))) void*)(b0 + k0),
                                         (__attribute__((address_space(3))) void*)sb0, 16, 0, 0);
        __builtin_amdgcn_global_load_lds((const __attribute__((address_space(1))) void*)(b1 + k0),
                                         (__attribute__((address_space(3))) void*)sb1, 16, 0, 0);
        __syncthreads();   // drains vmcnt before ds_read
        const int koff = (lane >> 4) * 8;
        f16x8 af[4], bf[4];
#pragma unroll
        for (int i = 0; i < 4; ++i) {
            af[i] = *(const f16x8*)&As[(wm + i * 16 + (lane & 15)) * 32 + koff];
            bf[i] = *(const f16x8*)&Bs[(wn + i * 16 + (lane & 15)) * 32 + koff];
        }
#pragma unroll
        for (int i = 0; i < 4; ++i)
#pragma unroll
            for (int j = 0; j < 4; ++j)
                acc[i][j] = __builtin_amdgcn_mfma_f32_16x16x32_f16(af[i], bf[j], acc[i][j], 0, 0, 0);
        __syncthreads();   // protect LDS before next stage
    }

    // epilogue: D row = (lane>>4)*4 + reg, col = lane&15 (verified m89/m91 layout)
    const long gr_base = bm * 128 + wm + (lane >> 4) * 4;
    const long gc_base = bn * 128 + wn + (lane & 15);
#pragma unroll
    for (int i = 0; i < 4; ++i) {
#pragma unroll
        for (int j = 0; j < 4; ++j) {
            const long gc = gc_base + j * 16;
            const float bv = bias ? bias[gc] : 0.0f;
#pragma unroll
            for (int r = 0; r < 4; ++r) {
                const long gr = gr_base + i * 16 + r;
                float v = acc[i][j][r] + bv;
                if (gelu) {
                    v = 0.5f * v * (1.0f + erff(v * 0.70710678118654752f));
                    Ch[gr * (long)N + gc] = (f16)v;
                } else {
                    if (resid) v += resid[gr * (long)N + gc];
                    Cf[gr * (long)N + gc] = v;
                }
            }
        }
    }
}

// ---------------- causal attention, fp32. qkv row: [3][H][DH]; one wave per query row ----------------
__global__ __launch_bounds__(256) void attn_k(const float* __restrict__ qkv, float* __restrict__ out) {
    __shared__ float sc[4][T_];
    __shared__ float qs[4][DH_];
    const int w = threadIdx.x >> 6, lane = threadIdx.x & 63;
    const int b = blockIdx.z, h = blockIdx.y;
    const int qi = blockIdx.x * 4 + w;
    const long rowq = ((long)(b * T_ + qi)) * (3 * D_);
    qs[w][lane] = qkv[rowq + h * DH_ + lane];
    __syncthreads();

    // scores: lane = key within 64-chunk
    for (int kb = 0; kb <= qi; kb += 64) {
        const int k = kb + lane;                 // always <= 1023 (kb <= 960)
        const float4* kp = (const float4*)(qkv + ((long)(b * T_ + k)) * (3 * D_) + D_ + h * DH_);
        float s = 0.0f;
#pragma unroll
        for (int d4 = 0; d4 < 16; ++d4) {
            const float4 kv = kp[d4];
            s += qs[w][d4 * 4 + 0] * kv.x + qs[w][d4 * 4 + 1] * kv.y +
                 qs[w][d4 * 4 + 2] * kv.z + qs[w][d4 * 4 + 3] * kv.w;
        }
        sc[w][k] = (k <= qi) ? s * 0.125f : -INFINITY;   // SCALE = DH^-0.5 = 1/8
    }

    // softmax over k in [0, qi]; padded tail holds -inf -> exp = 0
    const int nk  = qi + 1;
    const int nkp = (qi + 64) & ~63;
    float mx = -INFINITY;
    for (int k = lane; k < nkp; k += 64) mx = fmaxf(mx, sc[w][k]);
#pragma unroll
    for (int off = 32; off; off >>= 1) mx = fmaxf(mx, __shfl_xor(mx, off, 64));
    float sum = 0.0f;
    for (int k = lane; k < nkp; k += 64) {
        const float p = __expf(sc[w][k] - mx);
        sc[w][k] = p;
        sum += p;
    }
#pragma unroll
    for (int off = 32; off; off >>= 1) sum += __shfl_xor(sum, off, 64);
    const float inv = 1.0f / sum;

    // PV: lane = d
    float acc = 0.0f;
    const float* vp = qkv + (long)b * T_ * (3 * D_) + 2 * D_ + h * DH_ + lane;
#pragma unroll 4
    for (int k = 0; k < nk; ++k) acc += sc[w][k] * vp[(long)k * (3 * D_)];
    out[((long)(b * T_ + qi)) * D_ + h * DH_ + lane] = acc * inv;
}

// ---------------- host orchestration ----------------
extern "C" void kernel_launch(void* const* d_in, const int* in_sizes, int n_in,
                              void* d_out, int out_size, void* d_ws, size_t ws_size,
                              hipStream_t stream) {
    const int*   x    = (const int*)d_in[0];
    const float* emb  = (const float*)d_in[1];
    const float* pos  = (const float*)d_in[2];
    const float* Wqkv = (const float*)d_in[3];
    const float* bqkv = (const float*)d_in[4];
    const float* Wo   = (const float*)d_in[5];
    const float* bo   = (const float*)d_in[6];
    const float* Wg   = (const float*)d_in[7];
    const float* bg   = (const float*)d_in[8];
    const float* ln1g = (const float*)d_in[9];
    const float* ln1b = (const float*)d_in[10];
    const float* W1   = (const float*)d_in[11];
    const float* b1   = (const float*)d_in[12];
    const float* W2   = (const float*)d_in[13];
    const float* b2   = (const float*)d_in[14];
    const float* ln2g = (const float*)d_in[15];
    const float* ln2b = (const float*)d_in[16];
    const float* lnfg = (const float*)d_in[17];
    const float* lnfb = (const float*)d_in[18];
    float* out = (float*)d_out;

    char* ws = (char*)d_ws;
    size_t off = 0;
    auto alloc = [&](size_t bytes) -> void* {
        off = (off + 255) & ~(size_t)255;
        void* p = ws + off;
        off += bytes;
        return p;
    };
    float* h    = (float*)alloc((size_t)M_ * D_ * 4);
    float* n1f  = (float*)alloc((size_t)M_ * D_ * 4);
    float* qkvf = (float*)alloc((size_t)M_ * 3 * D_ * 4);
    float* pred = (float*)alloc((size_t)M_ * D_ * 4);
    float* corr = (float*)alloc((size_t)M_ * D_ * 4);
    float* glin = (float*)alloc((size_t)M_ * D_ * 4);
    f16* ab    = (f16*)alloc((size_t)M_ * D_ * 2);
    f16* catb  = (f16*)alloc((size_t)M_ * 2 * D_ * 2);
    f16* ffh   = (f16*)alloc((size_t)M_ * FF_ * 2);
    f16* embh  = (f16*)alloc((size_t)V_ * D_ * 2);
    f16* wqkvh = (f16*)alloc((size_t)L_ * 2 * 3 * D_ * D_ * 2);
    f16* woh   = (f16*)alloc((size_t)L_ * D_ * D_ * 2);
    f16* wgh   = (f16*)alloc((size_t)L_ * D_ * 2 * D_ * 2);
    f16* w1h   = (f16*)alloc((size_t)L_ * FF_ * D_ * 2);
    f16* w2h   = (f16*)alloc((size_t)L_ * D_ * FF_ * 2);

    auto cvt = [&](const float* src, f16* dst, long n) {
        f2h_k<<<dim3((unsigned)(n / 1024)), dim3(256), 0, stream>>>(src, dst);
    };
    cvt(emb,  embh,  (long)V_ * D_);
    cvt(Wqkv, wqkvh, (long)L_ * 2 * 3 * D_ * D_);
    cvt(Wo,   woh,   (long)L_ * D_ * D_);
    cvt(Wg,   wgh,   (long)L_ * D_ * 2 * D_);
    cvt(W1,   w1h,   (long)L_ * FF_ * D_);
    cvt(W2,   w2h,   (long)L_ * D_ * FF_);

    embed_k<<<dim3(M_), dim3(256), 0, stream>>>(x, emb, pos, h);

    auto gemm = [&](const f16* A, const f16* Wt, const float* bias, const float* resid,
                    float* Cf, f16* Ch, int N, int K, int gelu) {
        gemm_bt<<<dim3(N / 128, M_ / 128), dim3(256), 0, stream>>>(A, Wt, bias, resid, Cf, Ch, N, K, gelu);
    };

    for (int l = 0; l < L_; ++l) {
        ln_k<<<dim3(M_), 256, 0, stream>>>(h, ln1g + l * D_, ln1b + l * D_, n1f, ab);
        gemm(ab, wqkvh + (size_t)(l * 2 + 0) * 3 * D_ * D_, bqkv + (l * 2 + 0) * 3 * D_,
             nullptr, qkvf, nullptr, 3 * D_, D_, 0);
        attn_k<<<dim3(T_ / 4, H_, B_), 256, 0, stream>>>(qkvf, pred);
        sub_k<<<dim3(M_ * D_ / 1024), 256, 0, stream>>>(n1f, pred, ab);
        gemm(ab, wqkvh + (size_t)(l * 2 + 1) * 3 * D_ * D_, bqkv + (l * 2 + 1) * 3 * D_,
             nullptr, qkvf, nullptr, 3 * D_, D_, 0);
        attn_k<<<dim3(T_ / 4, H_, B_), 256, 0, stream>>>(qkvf, corr);
        cat_k<<<dim3(M_ * 2 * D_ / 1024), 256, 0, stream>>>(pred, corr, catb);
        gemm(catb, wgh + (size_t)l * D_ * 2 * D_, bg + l * D_, nullptr, glin, nullptr, D_, 2 * D_, 0);
        gate_k<<<dim3(M_ * D_ / 1024), 256, 0, stream>>>(pred, corr, glin, ab);
        gemm(ab, woh + (size_t)l * D_ * D_, bo + l * D_, h, h, nullptr, D_, D_, 0);
        ln_k<<<dim3(M_), 256, 0, stream>>>(h, ln2g + l * D_, ln2b + l * D_, nullptr, ab);
        gemm(ab, w1h + (size_t)l * FF_ * D_, b1 + l * FF_, nullptr, nullptr, ffh, FF_, D_, 1);
        gemm(ffh, w2h + (size_t)l * D_ * FF_, b2 + l * D_, h, h, nullptr, D_, FF_, 0);
    }
    ln_k<<<dim3(M_), 256, 0, stream>>>(h, lnfg, lnfb, nullptr, ab);
    gemm(ab, embh, nullptr, nullptr, out, nullptr, V_, D_, 0);
}